// Round 2
// baseline (1609.298 us; speedup 1.0000x reference)
//
#include <hip/hip_runtime.h>
#include <hip/hip_bf16.h>

#define NN   50000
#define CC   4
#define NNZV 800000
#define L0N  128

using bf16 = __hip_bfloat16;

__device__ __forceinline__ float bfu2f(unsigned short u) {
    union { unsigned int i; float f; } v;
    v.i = ((unsigned int)u) << 16;
    return v.f;
}
__device__ __forceinline__ float cvt(float x) { return x; }
__device__ __forceinline__ float cvt(bf16 x)  { return __bfloat162float(x); }
__device__ __forceinline__ unsigned short tobits(float x) {
    bf16 t = __float2bfloat16(x);
    return *(unsigned short*)&t;
}

// ---------------------------------------------------------------------------
// Kernel 0: runtime dtype detection.
// flags[0] = 1 if float inputs are f32 (else packed bf16)
// flags[1] = 1 if A is int64 (else int32)
// ---------------------------------------------------------------------------
__global__ void detect_kernel(const unsigned int* __restrict__ Xw,
                              const unsigned int* __restrict__ Aw,
                              int* __restrict__ flags) {
    __shared__ int cnt[2];
    const int t = threadIdx.x;            // 256 threads
    if (t < 2) cnt[t] = 0;
    __syncthreads();
    // float detector: low-16-bits of each word, bf16-exponent field bits[14:7].
    // Packed-bf16 data: this is a real N(0,1) bf16 exponent -> concentrated
    // around 126. f32 data: these are mantissa bits -> ~uniform.
    int c1 = 0;
    for (int i = t; i < 1024; i += 256) {
        unsigned b = (Xw[i] >> 7) & 0xFF;
        if (b >= 118 && b <= 134) c1++;
    }
    atomicAdd(&cnt[0], c1);
    // int64 detector: odd 32-bit words all zero (values < 2^32)
    int c2 = 0;
    if (t < 128) c2 = (Aw[2 * t + 1] == 0) ? 1 : 0;
    atomicAdd(&cnt[1], c2);
    __syncthreads();
    if (t == 0) {
        flags[0] = (cnt[0] < 512) ? 1 : 0;
        flags[1] = (cnt[1] >= 96) ? 1 : 0;
    }
}

// ---------------------------------------------------------------------------
// Kernel 1: XW[c][n][g] = sum_k X[n][k] * Ws[c][k][g]   (store bf16)
// ---------------------------------------------------------------------------
template<typename TF>
__device__ __forceinline__ void xw_body(const TF* __restrict__ X,
                                        const TF* __restrict__ Ws,
                                        unsigned short* __restrict__ XW,
                                        float* Xs, unsigned short* Wls) {
    const int n0 = blockIdx.x * 16;
    const int t  = threadIdx.x;
    for (int i = t; i < 16 * 64; i += 256)
        Xs[i] = cvt(X[n0 * 64 + i]);
    for (int i = t; i < CC * 64 * 64; i += 256)
        Wls[i] = tobits(cvt(Ws[i]));
    __syncthreads();
    const int c = t >> 6, g = t & 63;
    for (int n = 0; n < 16; ++n) {
        float acc = 0.f;
        #pragma unroll
        for (int k = 0; k < 64; ++k)
            acc = fmaf(Xs[n * 64 + k], bfu2f(Wls[(c * 64 + k) * 64 + g]), acc);
        XW[((size_t)c * NN + n0 + n) * 64 + g] = tobits(acc);
    }
}

__global__ __launch_bounds__(256) void xw_kernel(const void* __restrict__ X,
                                                 const void* __restrict__ Ws,
                                                 unsigned short* __restrict__ XW,
                                                 const int* __restrict__ flags) {
    __shared__ float Xs[16 * 64];
    __shared__ unsigned short Wls[CC * 64 * 64];
    if (flags[0]) xw_body<float>((const float*)X, (const float*)Ws, XW, Xs, Wls);
    else          xw_body<bf16> ((const bf16*)X,  (const bf16*)Ws,  XW, Xs, Wls);
}

// ---------------------------------------------------------------------------
// Kernel 2: scatter-add over edges. 32 threads/edge, ushort2 (2 g) each.
// H[dst, c*64+g] += XW[c][src][g]
// ---------------------------------------------------------------------------
template<typename TI>
__device__ __forceinline__ void scat_body(const TI* __restrict__ A,
                                          const unsigned short* __restrict__ XW,
                                          float* __restrict__ H) {
    const int t    = blockIdx.x * 256 + threadIdx.x;
    const int pair = t & 31;
    const int e    = t >> 5;              // global edge id, < 3,200,000
    const int c    = e / NNZV;
    const int ei   = e - c * NNZV;
    const int dst  = (int)A[(size_t)(c * 2 + 0) * NNZV + ei];
    const int src  = (int)A[(size_t)(c * 2 + 1) * NNZV + ei];
    if ((unsigned)dst >= NN || (unsigned)src >= NN) return;   // safety clamp
    const ushort2 uv = *(const ushort2*)(XW + ((size_t)c * NN + src) * 64 + 2 * pair);
    float* hp = H + ((size_t)dst * 256 + c * 64 + 2 * pair);
    atomicAdd(hp,     bfu2f(uv.x));
    atomicAdd(hp + 1, bfu2f(uv.y));
}

__global__ __launch_bounds__(256) void scatter_kernel(const void* __restrict__ A,
                                                      const unsigned short* __restrict__ XW,
                                                      float* __restrict__ H,
                                                      const int* __restrict__ flags) {
    if (flags[1]) scat_body<long long>((const long long*)A, XW, H);
    else          scat_body<int>      ((const int*)A,       XW, H);
}

// ---------------------------------------------------------------------------
// Kernel 3: h = H @ W0 + b0  (K=256 -> 128 cols), fused BN partial sums.
// ---------------------------------------------------------------------------
template<typename TF>
__device__ __forceinline__ void l0_body(const float* __restrict__ H,
                                        const TF* __restrict__ W0,
                                        const TF* __restrict__ b0,
                                        float* __restrict__ h,
                                        float* __restrict__ stats,
                                        float* Hs, float* psum, float* psq) {
    const int n0 = blockIdx.x * 16;
    const int t  = threadIdx.x;
    {
        const float4* src4 = (const float4*)(H + (size_t)n0 * 256);
        float4* dst4 = (float4*)Hs;
        for (int i = t; i < 16 * 64; i += 256) dst4[i] = src4[i];
    }
    if (t < L0N) { psum[t] = 0.f; psq[t] = 0.f; }
    __syncthreads();
    const int j  = t & 127;
    const int rh = t >> 7;   // 0 or 1
    float acc[8];
    #pragma unroll
    for (int r = 0; r < 8; ++r) acc[r] = 0.f;
    for (int k = 0; k < 256; ++k) {
        float w = cvt(W0[k * 128 + j]);
        #pragma unroll
        for (int r = 0; r < 8; ++r)
            acc[r] = fmaf(Hs[(rh * 8 + r) * 256 + k], w, acc[r]);
    }
    const float bj = cvt(b0[j]);
    float s = 0.f, ss = 0.f;
    #pragma unroll
    for (int r = 0; r < 8; ++r) {
        float v = acc[r] + bj;
        h[(size_t)(n0 + rh * 8 + r) * 128 + j] = v;
        s += v; ss += v * v;
    }
    atomicAdd(&psum[j], s);
    atomicAdd(&psq[j], ss);
    __syncthreads();
    if (t < L0N) {
        atomicAdd(&stats[t],       psum[t]);
        atomicAdd(&stats[L0N + t], psq[t]);
    }
}

__global__ __launch_bounds__(256) void l0_kernel(const float* __restrict__ H,
                                                 const void* __restrict__ W0,
                                                 const void* __restrict__ b0,
                                                 float* __restrict__ h,
                                                 float* __restrict__ stats,
                                                 const int* __restrict__ flags) {
    __shared__ float Hs[16 * 256];
    __shared__ float psum[L0N], psq[L0N];
    if (flags[0]) l0_body<float>(H, (const float*)W0, (const float*)b0, h, stats, Hs, psum, psq);
    else          l0_body<bf16> (H, (const bf16*)W0,  (const bf16*)b0,  h, stats, Hs, psum, psq);
}

// ---------------------------------------------------------------------------
// Kernel 4: fold BN stats into per-column affine: bn(x) = a*x + b
// ---------------------------------------------------------------------------
template<typename TF>
__device__ __forceinline__ void bn_body(const float* __restrict__ stats,
                                        const TF* __restrict__ gamma,
                                        const TF* __restrict__ beta,
                                        float* __restrict__ coef) {
    const int j = threadIdx.x;   // 128 threads
    const float invN = 1.0f / (float)NN;
    const float mean = stats[j] * invN;
    const float var  = stats[L0N + j] * invN - mean * mean;
    const float inv  = rsqrtf(var + 1e-5f);
    const float a = cvt(gamma[j]) * inv;
    const float b = cvt(beta[j]) - mean * a;
    coef[j] = a;
    coef[L0N + j] = b;
}

__global__ void bn_kernel(const float* __restrict__ stats,
                          const void* __restrict__ gamma,
                          const void* __restrict__ beta,
                          float* __restrict__ coef,
                          const int* __restrict__ flags) {
    if (flags[0]) bn_body<float>(stats, (const float*)gamma, (const float*)beta, coef);
    else          bn_body<bf16> (stats, (const bf16*)gamma,  (const bf16*)beta,  coef);
}

// ---------------------------------------------------------------------------
// Kernel 5: out = elu(bn(h)) @ W1 + b1  -> [N,64] in matching dtype
// ---------------------------------------------------------------------------
template<typename TF>
__device__ __forceinline__ void l1_body(const float* __restrict__ h,
                                        const float* __restrict__ coef,
                                        const TF* __restrict__ W1,
                                        const TF* __restrict__ b1,
                                        void* __restrict__ outv,
                                        float* Es) {
    const int n0 = blockIdx.x * 16;
    const int t  = threadIdx.x;
    for (int i = t; i < 16 * 128; i += 256) {
        const int k = i & 127;
        float v = h[(size_t)n0 * 128 + i];
        v = coef[k] * v + coef[L0N + k];
        Es[i] = v > 0.f ? v : expm1f(v);
    }
    __syncthreads();
    const int j  = t & 63;
    const int rq = t >> 6;   // 0..3
    float acc[4] = {0.f, 0.f, 0.f, 0.f};
    for (int k = 0; k < 128; ++k) {
        float w = cvt(W1[k * 64 + j]);
        #pragma unroll
        for (int r = 0; r < 4; ++r)
            acc[r] = fmaf(Es[(rq * 4 + r) * 128 + k], w, acc[r]);
    }
    const float bj = cvt(b1[j]);
    #pragma unroll
    for (int r = 0; r < 4; ++r) {
        const size_t oidx = (size_t)(n0 + rq * 4 + r) * 64 + j;
        const float v = acc[r] + bj;
        if (sizeof(TF) == 4) ((float*)outv)[oidx] = v;
        else                 ((unsigned short*)outv)[oidx] = tobits(v);
    }
}

__global__ __launch_bounds__(256) void l1_kernel(const float* __restrict__ h,
                                                 const float* __restrict__ coef,
                                                 const void* __restrict__ W1,
                                                 const void* __restrict__ b1,
                                                 void* __restrict__ out,
                                                 const int* __restrict__ flags) {
    __shared__ float Es[16 * 128];
    if (flags[0]) l1_body<float>(h, coef, (const float*)W1, (const float*)b1, out, Es);
    else          l1_body<bf16> (h, coef, (const bf16*)W1,  (const bf16*)b1,  out, Es);
}

// ---------------------------------------------------------------------------
// Workspace layout (bytes):
//   H      : [N,256] f32          @ 0            51,200,000
//   stats  : [256]   f32          @ 51,200,000    1,024   (zeroed with H)
//   coef   : [256]   f32          @ 51,201,024    1,024
//   flags  : [2]     i32          @ 51,202,048      256
//   XW     : [C,N,64] bf16        @ 51,202,304   25,600,000
//   h      : [N,128] f32          @ 51,202,304   (ALIASES XW — XW dead after scatter)
// total 76,802,304 B  (~73.2 MiB)
// ---------------------------------------------------------------------------
extern "C" void kernel_launch(void* const* d_in, const int* in_sizes, int n_in,
                              void* d_out, int out_size, void* d_ws, size_t ws_size,
                              hipStream_t stream) {
    const void* A     = d_in[0];
    const void* X     = d_in[1];
    const void* Ws    = d_in[2];
    const void* W0    = d_in[3];
    const void* b0    = d_in[4];
    const void* gamma = d_in[5];
    const void* beta  = d_in[6];
    const void* W1    = d_in[7];
    const void* b1    = d_in[8];

    char* ws = (char*)d_ws;
    float*          H     = (float*)(ws);
    float*          stats = (float*)(ws + 51200000);
    float*          coef  = (float*)(ws + 51201024);
    int*            flags = (int*)  (ws + 51202048);
    unsigned short* XW    = (unsigned short*)(ws + 51202304);
    float*          h     = (float*)(ws + 51202304);   // alias XW (dead after scatter)

    detect_kernel<<<1, 256, 0, stream>>>((const unsigned int*)X, (const unsigned int*)A, flags);
    hipMemsetAsync(H, 0, 51200000 + 1024, stream);   // zero H + stats every call

    xw_kernel     <<<NN / 16, 256, 0, stream>>>(X, Ws, XW, flags);
    scatter_kernel<<<(CC * NNZV * 32) / 256, 256, 0, stream>>>(A, XW, H, flags);
    l0_kernel     <<<NN / 16, 256, 0, stream>>>(H, W0, b0, h, stats, flags);
    bn_kernel     <<<1, 128, 0, stream>>>(stats, gamma, beta, coef, flags);
    l1_kernel     <<<NN / 16, 256, 0, stream>>>(h, coef, W1, b1, d_out, flags);
}

// Round 3
// 741.837 us; speedup vs baseline: 2.1693x; 2.1693x over previous
//
#include <hip/hip_runtime.h>
#include <hip/hip_bf16.h>

#define NN   50000
#define CC   4
#define NNZV 800000
#define L0N  128
#define MSEG (CC * NN)                 // 200,000 CSR segments
#define NBLK ((MSEG + 1023) / 1024)    // 196 scan blocks

using bf16 = __hip_bfloat16;

__device__ __forceinline__ float bfu2f(unsigned short u) {
    union { unsigned int i; float f; } v;
    v.i = ((unsigned int)u) << 16;
    return v.f;
}
__device__ __forceinline__ float cvt(float x) { return x; }
__device__ __forceinline__ float cvt(bf16 x)  { return __bfloat162float(x); }
__device__ __forceinline__ unsigned short tobits(float x) {
    bf16 t = __float2bfloat16(x);
    return *(unsigned short*)&t;
}

// ---------------------------------------------------------------------------
// Kernel 0: runtime dtype detection (proven working in round 2).
// flags[0] = 1 if float inputs are f32; flags[1] = 1 if A is int64
// ---------------------------------------------------------------------------
__global__ void detect_kernel(const unsigned int* __restrict__ Xw,
                              const unsigned int* __restrict__ Aw,
                              int* __restrict__ flags) {
    __shared__ int cnt[2];
    const int t = threadIdx.x;            // 256 threads
    if (t < 2) cnt[t] = 0;
    __syncthreads();
    int c1 = 0;
    for (int i = t; i < 1024; i += 256) {
        unsigned b = (Xw[i] >> 7) & 0xFF;
        if (b >= 118 && b <= 134) c1++;
    }
    atomicAdd(&cnt[0], c1);
    int c2 = 0;
    if (t < 128) c2 = (Aw[2 * t + 1] == 0) ? 1 : 0;
    atomicAdd(&cnt[1], c2);
    __syncthreads();
    if (t == 0) {
        flags[0] = (cnt[0] < 512) ? 1 : 0;
        flags[1] = (cnt[1] >= 96) ? 1 : 0;
    }
}

// ---------------------------------------------------------------------------
// Kernel 1: XW[c][n][g] = sum_k X[n][k] * Ws[c][k][g]   (store bf16)
// ---------------------------------------------------------------------------
template<typename TF>
__device__ __forceinline__ void xw_body(const TF* __restrict__ X,
                                        const TF* __restrict__ Ws,
                                        unsigned short* __restrict__ XW,
                                        float* Xs, unsigned short* Wls) {
    const int n0 = blockIdx.x * 16;
    const int t  = threadIdx.x;
    for (int i = t; i < 16 * 64; i += 256)
        Xs[i] = cvt(X[n0 * 64 + i]);
    for (int i = t; i < CC * 64 * 64; i += 256)
        Wls[i] = tobits(cvt(Ws[i]));
    __syncthreads();
    const int c = t >> 6, g = t & 63;
    for (int n = 0; n < 16; ++n) {
        float acc = 0.f;
        #pragma unroll
        for (int k = 0; k < 64; ++k)
            acc = fmaf(Xs[n * 64 + k], bfu2f(Wls[(c * 64 + k) * 64 + g]), acc);
        XW[((size_t)c * NN + n0 + n) * 64 + g] = tobits(acc);
    }
}

__global__ __launch_bounds__(256) void xw_kernel(const void* __restrict__ X,
                                                 const void* __restrict__ Ws,
                                                 unsigned short* __restrict__ XW,
                                                 const int* __restrict__ flags) {
    __shared__ float Xs[16 * 64];
    __shared__ unsigned short Wls[CC * 64 * 64];
    if (flags[0]) xw_body<float>((const float*)X, (const float*)Ws, XW, Xs, Wls);
    else          xw_body<bf16> ((const bf16*)X,  (const bf16*)Ws,  XW, Xs, Wls);
}

// ---------------------------------------------------------------------------
// CSR build: count -> scan (3 passes) -> fill
// ---------------------------------------------------------------------------
template<typename TI>
__device__ __forceinline__ void count_body(const TI* __restrict__ A,
                                           int* __restrict__ cnt) {
    const int e = blockIdx.x * 256 + threadIdx.x;
    if (e >= CC * NNZV) return;
    const int c  = e / NNZV;
    const int ei = e - c * NNZV;
    const int dst = (int)A[(size_t)(c * 2 + 0) * NNZV + ei];
    if ((unsigned)dst >= NN) return;
    atomicAdd(&cnt[c * NN + dst], 1);
}

__global__ __launch_bounds__(256) void count_kernel(const void* __restrict__ A,
                                                    int* __restrict__ cnt,
                                                    const int* __restrict__ flags) {
    if (flags[1]) count_body<long long>((const long long*)A, cnt);
    else          count_body<int>      ((const int*)A,       cnt);
}

// pass 1: per-1024-block local exclusive scan -> offs, block totals -> bsums
__global__ __launch_bounds__(256) void scan1_kernel(const int* __restrict__ cnt,
                                                    int* __restrict__ offs,
                                                    int* __restrict__ bsums) {
    __shared__ int ts[256];
    const int t = threadIdx.x;
    const int base = blockIdx.x * 1024 + t * 4;
    int v[4], s = 0;
    #pragma unroll
    for (int r = 0; r < 4; ++r) {
        v[r] = (base + r < MSEG) ? cnt[base + r] : 0;
        s += v[r];
    }
    ts[t] = s;
    __syncthreads();
    for (int off = 1; off < 256; off <<= 1) {
        int val = (t >= off) ? ts[t - off] : 0;
        __syncthreads();
        ts[t] += val;
        __syncthreads();
    }
    int ex = ts[t] - s;   // exclusive prefix of this thread's chunk
    #pragma unroll
    for (int r = 0; r < 4; ++r) {
        if (base + r < MSEG) offs[base + r] = ex;
        ex += v[r];
    }
    if (t == 255) bsums[blockIdx.x] = ts[255];
}

// pass 2: single-block exclusive scan of NBLK block totals
__global__ __launch_bounds__(256) void scan2_kernel(const int* __restrict__ bsums,
                                                    int* __restrict__ bscan) {
    __shared__ int ts[256];
    const int t = threadIdx.x;
    int s = (t < NBLK) ? bsums[t] : 0;
    ts[t] = s;
    __syncthreads();
    for (int off = 1; off < 256; off <<= 1) {
        int val = (t >= off) ? ts[t - off] : 0;
        __syncthreads();
        ts[t] += val;
        __syncthreads();
    }
    if (t < NBLK) bscan[t] = ts[t] - s;
}

// pass 3: add block offsets; also init cursor = offs
__global__ __launch_bounds__(256) void scan3_kernel(int* __restrict__ offs,
                                                    const int* __restrict__ bscan,
                                                    int* __restrict__ cursor) {
    const int t = threadIdx.x;
    const int base = blockIdx.x * 1024 + t * 4;
    const int add = bscan[blockIdx.x];
    #pragma unroll
    for (int r = 0; r < 4; ++r) {
        if (base + r < MSEG) {
            int o = offs[base + r] + add;
            offs[base + r] = o;
            cursor[base + r] = o;
        }
    }
}

template<typename TI>
__device__ __forceinline__ void fill_body(const TI* __restrict__ A,
                                          int* __restrict__ cursor,
                                          unsigned short* __restrict__ edge_src) {
    const int e = blockIdx.x * 256 + threadIdx.x;
    if (e >= CC * NNZV) return;
    const int c  = e / NNZV;
    const int ei = e - c * NNZV;
    const int dst = (int)A[(size_t)(c * 2 + 0) * NNZV + ei];
    const int src = (int)A[(size_t)(c * 2 + 1) * NNZV + ei];
    if ((unsigned)dst >= NN || (unsigned)src >= NN) return;
    const int pos = atomicAdd(&cursor[c * NN + dst], 1);
    edge_src[pos] = (unsigned short)src;
}

__global__ __launch_bounds__(256) void fill_kernel(const void* __restrict__ A,
                                                   int* __restrict__ cursor,
                                                   unsigned short* __restrict__ edge_src,
                                                   const int* __restrict__ flags) {
    if (flags[1]) fill_body<long long>((const long long*)A, cursor, edge_src);
    else          fill_body<int>      ((const int*)A,       cursor, edge_src);
}

// ---------------------------------------------------------------------------
// Kernel 2: gather. One wave per (dst, c) segment; lane = g.
// block 256 = 4 waves = the 4 categories of one dst -> H row written whole.
// ---------------------------------------------------------------------------
__global__ __launch_bounds__(256) void gather_kernel(const unsigned short* __restrict__ edge_src,
                                                     const int* __restrict__ offs,
                                                     const int* __restrict__ cnt,
                                                     const unsigned short* __restrict__ XW,
                                                     float* __restrict__ H) {
    const int t   = threadIdx.x;
    const int c   = t >> 6;          // wave index = category
    const int g   = t & 63;
    const int dst = blockIdx.x;
    const int seg = c * NN + dst;
    const int beg = offs[seg];
    const int n   = cnt[seg];
    const unsigned short* xwg = XW + (size_t)c * NN * 64 + g;
    const unsigned short* ep  = edge_src + beg;
    float acc = 0.f;
    int e = 0;
    for (; e + 4 <= n; e += 4) {
        const int s0 = ep[e], s1 = ep[e + 1], s2 = ep[e + 2], s3 = ep[e + 3];
        const float a0 = bfu2f(xwg[(size_t)s0 * 64]);
        const float a1 = bfu2f(xwg[(size_t)s1 * 64]);
        const float a2 = bfu2f(xwg[(size_t)s2 * 64]);
        const float a3 = bfu2f(xwg[(size_t)s3 * 64]);
        acc += (a0 + a1) + (a2 + a3);
    }
    for (; e < n; ++e)
        acc += bfu2f(xwg[(size_t)ep[e] * 64]);
    H[(size_t)dst * 256 + c * 64 + g] = acc;
}

// ---------------------------------------------------------------------------
// Kernel 3: h = H @ W0 + b0  (K=256 -> 128 cols), fused BN partial sums.
// ---------------------------------------------------------------------------
template<typename TF>
__device__ __forceinline__ void l0_body(const float* __restrict__ H,
                                        const TF* __restrict__ W0,
                                        const TF* __restrict__ b0,
                                        float* __restrict__ h,
                                        float* __restrict__ stats,
                                        float* Hs, float* psum, float* psq) {
    const int n0 = blockIdx.x * 16;
    const int t  = threadIdx.x;
    {
        const float4* src4 = (const float4*)(H + (size_t)n0 * 256);
        float4* dst4 = (float4*)Hs;
        for (int i = t; i < 16 * 64; i += 256) dst4[i] = src4[i];
    }
    if (t < L0N) { psum[t] = 0.f; psq[t] = 0.f; }
    __syncthreads();
    const int j  = t & 127;
    const int rh = t >> 7;   // 0 or 1
    float acc[8];
    #pragma unroll
    for (int r = 0; r < 8; ++r) acc[r] = 0.f;
    for (int k = 0; k < 256; ++k) {
        float w = cvt(W0[k * 128 + j]);
        #pragma unroll
        for (int r = 0; r < 8; ++r)
            acc[r] = fmaf(Hs[(rh * 8 + r) * 256 + k], w, acc[r]);
    }
    const float bj = cvt(b0[j]);
    float s = 0.f, ss = 0.f;
    #pragma unroll
    for (int r = 0; r < 8; ++r) {
        float v = acc[r] + bj;
        h[(size_t)(n0 + rh * 8 + r) * 128 + j] = v;
        s += v; ss += v * v;
    }
    atomicAdd(&psum[j], s);
    atomicAdd(&psq[j], ss);
    __syncthreads();
    if (t < L0N) {
        atomicAdd(&stats[t],       psum[t]);
        atomicAdd(&stats[L0N + t], psq[t]);
    }
}

__global__ __launch_bounds__(256) void l0_kernel(const float* __restrict__ H,
                                                 const void* __restrict__ W0,
                                                 const void* __restrict__ b0,
                                                 float* __restrict__ h,
                                                 float* __restrict__ stats,
                                                 const int* __restrict__ flags) {
    __shared__ float Hs[16 * 256];
    __shared__ float psum[L0N], psq[L0N];
    if (flags[0]) l0_body<float>(H, (const float*)W0, (const float*)b0, h, stats, Hs, psum, psq);
    else          l0_body<bf16> (H, (const bf16*)W0,  (const bf16*)b0,  h, stats, Hs, psum, psq);
}

// ---------------------------------------------------------------------------
// Kernel 4: fold BN stats into per-column affine: bn(x) = a*x + b
// ---------------------------------------------------------------------------
template<typename TF>
__device__ __forceinline__ void bn_body(const float* __restrict__ stats,
                                        const TF* __restrict__ gamma,
                                        const TF* __restrict__ beta,
                                        float* __restrict__ coef) {
    const int j = threadIdx.x;   // 128 threads
    const float invN = 1.0f / (float)NN;
    const float mean = stats[j] * invN;
    const float var  = stats[L0N + j] * invN - mean * mean;
    const float inv  = rsqrtf(var + 1e-5f);
    const float a = cvt(gamma[j]) * inv;
    const float b = cvt(beta[j]) - mean * a;
    coef[j] = a;
    coef[L0N + j] = b;
}

__global__ void bn_kernel(const float* __restrict__ stats,
                          const void* __restrict__ gamma,
                          const void* __restrict__ beta,
                          float* __restrict__ coef,
                          const int* __restrict__ flags) {
    if (flags[0]) bn_body<float>(stats, (const float*)gamma, (const float*)beta, coef);
    else          bn_body<bf16> (stats, (const bf16*)gamma,  (const bf16*)beta,  coef);
}

// ---------------------------------------------------------------------------
// Kernel 5: out = elu(bn(h)) @ W1 + b1  -> [N,64] in matching dtype
// ---------------------------------------------------------------------------
template<typename TF>
__device__ __forceinline__ void l1_body(const float* __restrict__ h,
                                        const float* __restrict__ coef,
                                        const TF* __restrict__ W1,
                                        const TF* __restrict__ b1,
                                        void* __restrict__ outv,
                                        float* Es) {
    const int n0 = blockIdx.x * 16;
    const int t  = threadIdx.x;
    for (int i = t; i < 16 * 128; i += 256) {
        const int k = i & 127;
        float v = h[(size_t)n0 * 128 + i];
        v = coef[k] * v + coef[L0N + k];
        Es[i] = v > 0.f ? v : expm1f(v);
    }
    __syncthreads();
    const int j  = t & 63;
    const int rq = t >> 6;   // 0..3
    float acc[4] = {0.f, 0.f, 0.f, 0.f};
    for (int k = 0; k < 128; ++k) {
        float w = cvt(W1[k * 64 + j]);
        #pragma unroll
        for (int r = 0; r < 4; ++r)
            acc[r] = fmaf(Es[(rq * 4 + r) * 128 + k], w, acc[r]);
    }
    const float bj = cvt(b1[j]);
    #pragma unroll
    for (int r = 0; r < 4; ++r) {
        const size_t oidx = (size_t)(n0 + rq * 4 + r) * 64 + j;
        const float v = acc[r] + bj;
        if (sizeof(TF) == 4) ((float*)outv)[oidx] = v;
        else                 ((unsigned short*)outv)[oidx] = tobits(v);
    }
}

__global__ __launch_bounds__(256) void l1_kernel(const float* __restrict__ h,
                                                 const float* __restrict__ coef,
                                                 const void* __restrict__ W1,
                                                 const void* __restrict__ b1,
                                                 void* __restrict__ out,
                                                 const int* __restrict__ flags) {
    __shared__ float Es[16 * 128];
    if (flags[0]) l1_body<float>(h, coef, (const float*)W1, (const float*)b1, out, Es);
    else          l1_body<bf16> (h, coef, (const bf16*)W1,  (const bf16*)b1,  out, Es);
}

// ---------------------------------------------------------------------------
// Workspace layout (bytes):
//   H        : [N,256] f32     @ 0             51,200,000
//   stats    : [256]   f32     @ 51,200,000     1,024
//   coef     : [256]   f32     @ 51,201,024     1,024
//   flags    : [2]     i32     @ 51,202,048       256
//   XW       : [C,N,64] bf16   @ 51,202,304    25,600,000   (h aliases after gather)
//   cnt      : [200000] i32    @ 76,802,304       800,000
//   offs     : [200000] i32    @ 77,602,304       800,000
//   cursor   : [200000] i32    @ 78,402,304       800,000
//   bsums    : [196]    i32    @ 79,202,304         1,024
//   bscan    : [196]    i32    @ 79,203,328         1,024
//   edge_src : [3.2M]  u16     @ 79,204,352     6,400,000
// total 85,604,352 B (~81.6 MiB)
// ---------------------------------------------------------------------------
extern "C" void kernel_launch(void* const* d_in, const int* in_sizes, int n_in,
                              void* d_out, int out_size, void* d_ws, size_t ws_size,
                              hipStream_t stream) {
    const void* A     = d_in[0];
    const void* X     = d_in[1];
    const void* Ws    = d_in[2];
    const void* W0    = d_in[3];
    const void* b0    = d_in[4];
    const void* gamma = d_in[5];
    const void* beta  = d_in[6];
    const void* W1    = d_in[7];
    const void* b1    = d_in[8];

    char* ws = (char*)d_ws;
    float*          H        = (float*)(ws);
    float*          stats    = (float*)(ws + 51200000);
    float*          coef     = (float*)(ws + 51201024);
    int*            flags    = (int*)  (ws + 51202048);
    unsigned short* XW       = (unsigned short*)(ws + 51202304);
    float*          h        = (float*)(ws + 51202304);   // alias XW (dead after gather... used by l0 AFTER gather+l0 input H)
    int*            cnt      = (int*)  (ws + 76802304);
    int*            offs     = (int*)  (ws + 77602304);
    int*            cursor   = (int*)  (ws + 78402304);
    int*            bsums    = (int*)  (ws + 79202304);
    int*            bscan    = (int*)  (ws + 79203328);
    unsigned short* edge_src = (unsigned short*)(ws + 79204352);

    detect_kernel<<<1, 256, 0, stream>>>((const unsigned int*)X, (const unsigned int*)A, flags);
    hipMemsetAsync(cnt, 0, 800000, stream);     // zero counts every call
    hipMemsetAsync(stats, 0, 1024, stream);     // zero BN stats every call

    xw_kernel   <<<NN / 16, 256, 0, stream>>>(X, Ws, XW, flags);
    count_kernel<<<(CC * NNZV + 255) / 256, 256, 0, stream>>>(A, cnt, flags);
    scan1_kernel<<<NBLK, 256, 0, stream>>>(cnt, offs, bsums);
    scan2_kernel<<<1, 256, 0, stream>>>(bsums, bscan);
    scan3_kernel<<<NBLK, 256, 0, stream>>>(offs, bscan, cursor);
    fill_kernel <<<(CC * NNZV + 255) / 256, 256, 0, stream>>>(A, cursor, edge_src, flags);
    gather_kernel<<<NN, 256, 0, stream>>>(edge_src, offs, cnt, XW, H);
    l0_kernel   <<<NN / 16, 256, 0, stream>>>(H, W0, b0, h, stats, flags);
    bn_kernel   <<<1, 128, 0, stream>>>(stats, gamma, beta, coef, flags);
    l1_kernel   <<<NN / 16, 256, 0, stream>>>(h, coef, W1, b1, d_out, flags);
}

// Round 4
// 506.606 us; speedup vs baseline: 3.1766x; 1.4643x over previous
//
#include <hip/hip_runtime.h>
#include <hip/hip_bf16.h>

#define NN    50000
#define CC    4
#define NNZV  800000
#define L0N   128
#define TOTE  (CC * NNZV)          // 3,200,000 edges
#define NWG   1024                 // workgroups for hist/cscatter
#define EPW   (TOTE / NWG)         // 3125 edges per WG (exact)
#define NBKT  256                  // dst buckets (dst >> 8); only 196 non-empty

using bf16 = __hip_bfloat16;

__device__ __forceinline__ float bfu2f(unsigned short u) {
    union { unsigned int i; float f; } v;
    v.i = ((unsigned int)u) << 16;
    return v.f;
}
__device__ __forceinline__ float cvt(float x) { return x; }
__device__ __forceinline__ float cvt(bf16 x)  { return __bfloat162float(x); }
__device__ __forceinline__ unsigned short tobits(float x) {
    bf16 t = __float2bfloat16(x);
    return *(unsigned short*)&t;
}

// ---------------------------------------------------------------------------
// Kernel 0: runtime dtype detection (proven in rounds 2-3).
// flags[0] = 1 if float inputs are f32; flags[1] = 1 if A is int64
// ---------------------------------------------------------------------------
__global__ void detect_kernel(const unsigned int* __restrict__ Xw,
                              const unsigned int* __restrict__ Aw,
                              int* __restrict__ flags) {
    __shared__ int cnt[2];
    const int t = threadIdx.x;            // 256 threads
    if (t < 2) cnt[t] = 0;
    __syncthreads();
    int c1 = 0;
    for (int i = t; i < 1024; i += 256) {
        unsigned b = (Xw[i] >> 7) & 0xFF;
        if (b >= 118 && b <= 134) c1++;
    }
    atomicAdd(&cnt[0], c1);
    int c2 = 0;
    if (t < 128) c2 = (Aw[2 * t + 1] == 0) ? 1 : 0;
    atomicAdd(&cnt[1], c2);
    __syncthreads();
    if (t == 0) {
        flags[0] = (cnt[0] < 512) ? 1 : 0;
        flags[1] = (cnt[1] >= 96) ? 1 : 0;
    }
}

// ---------------------------------------------------------------------------
// Kernel 1: XW[c][n][g] = sum_k X[n][k] * Ws[c][k][g]   (store bf16)
// ---------------------------------------------------------------------------
template<typename TF>
__device__ __forceinline__ void xw_body(const TF* __restrict__ X,
                                        const TF* __restrict__ Ws,
                                        unsigned short* __restrict__ XW,
                                        float* Xs, unsigned short* Wls) {
    const int n0 = blockIdx.x * 16;
    const int t  = threadIdx.x;
    for (int i = t; i < 16 * 64; i += 256)
        Xs[i] = cvt(X[n0 * 64 + i]);
    for (int i = t; i < CC * 64 * 64; i += 256)
        Wls[i] = tobits(cvt(Ws[i]));
    __syncthreads();
    const int c = t >> 6, g = t & 63;
    for (int n = 0; n < 16; ++n) {
        float acc = 0.f;
        #pragma unroll
        for (int k = 0; k < 64; ++k)
            acc = fmaf(Xs[n * 64 + k], bfu2f(Wls[(c * 64 + k) * 64 + g]), acc);
        XW[((size_t)c * NN + n0 + n) * 64 + g] = tobits(acc);
    }
}

__global__ __launch_bounds__(256) void xw_kernel(const void* __restrict__ X,
                                                 const void* __restrict__ Ws,
                                                 unsigned short* __restrict__ XW,
                                                 const int* __restrict__ flags) {
    __shared__ float Xs[16 * 64];
    __shared__ unsigned short Wls[CC * 64 * 64];
    if (flags[0]) xw_body<float>((const float*)X, (const float*)Ws, XW, Xs, Wls);
    else          xw_body<bf16> ((const bf16*)X,  (const bf16*)Ws,  XW, Xs, Wls);
}

// ---------------------------------------------------------------------------
// CSR build, bucketed: hist -> scan(262144) -> cscatter -> dfinal
// ---------------------------------------------------------------------------
template<typename TI>
__device__ __forceinline__ void hist_body(const TI* __restrict__ A,
                                          unsigned int* __restrict__ hist,
                                          unsigned int* lh) {
    const int w = blockIdx.x, t = threadIdx.x;
    lh[t] = 0;
    __syncthreads();
    const int base = w * EPW;
    for (int i = t; i < EPW; i += 256) {
        const int e  = base + i;
        const int c  = e / NNZV;
        const int ei = e - c * NNZV;
        const int dst = (int)A[(size_t)(c * 2) * NNZV + ei];
        if ((unsigned)dst < NN) atomicAdd(&lh[dst >> 8], 1u);
    }
    __syncthreads();
    hist[(size_t)t * NWG + w] = lh[t];    // bucket-major [bucket][wg]
}

__global__ __launch_bounds__(256) void hist_kernel(const void* __restrict__ A,
                                                   unsigned int* __restrict__ hist,
                                                   const int* __restrict__ flags) {
    __shared__ unsigned int lh[NBKT];
    if (flags[1]) hist_body<long long>((const long long*)A, hist, lh);
    else          hist_body<int>      ((const int*)A,       hist, lh);
}

// scan pass 1: 256 blocks x 1024 elems, local exclusive scan + block totals
__global__ __launch_bounds__(256) void scan1_kernel(const unsigned int* __restrict__ in,
                                                    unsigned int* __restrict__ out,
                                                    unsigned int* __restrict__ bsums) {
    __shared__ unsigned int ts[256];
    const int t = threadIdx.x;
    const int base = blockIdx.x * 1024 + t * 4;
    uint4 v = *(const uint4*)(in + base);
    unsigned int s = v.x + v.y + v.z + v.w;
    ts[t] = s;
    __syncthreads();
    for (int off = 1; off < 256; off <<= 1) {
        unsigned int val = (t >= off) ? ts[t - off] : 0;
        __syncthreads();
        ts[t] += val;
        __syncthreads();
    }
    unsigned int ex = ts[t] - s;
    uint4 o;
    o.x = ex; o.y = ex + v.x; o.z = ex + v.x + v.y; o.w = ex + v.x + v.y + v.z;
    *(uint4*)(out + base) = o;
    if (t == 255) bsums[blockIdx.x] = ts[255];
}

// scan pass 2: single block, exclusive scan of 256 block totals
__global__ __launch_bounds__(256) void scan2_kernel(const unsigned int* __restrict__ bsums,
                                                    unsigned int* __restrict__ bscan) {
    __shared__ unsigned int ts[256];
    const int t = threadIdx.x;
    unsigned int s = bsums[t];
    ts[t] = s;
    __syncthreads();
    for (int off = 1; off < 256; off <<= 1) {
        unsigned int val = (t >= off) ? ts[t - off] : 0;
        __syncthreads();
        ts[t] += val;
        __syncthreads();
    }
    bscan[t] = ts[t] - s;
}

// scan pass 3: add block offsets
__global__ __launch_bounds__(256) void scan3_kernel(unsigned int* __restrict__ out,
                                                    const unsigned int* __restrict__ bscan) {
    const int base = blockIdx.x * 1024 + threadIdx.x * 4;
    const unsigned int add = bscan[blockIdx.x];
    uint4 v = *(uint4*)(out + base);
    v.x += add; v.y += add; v.z += add; v.w += add;
    *(uint4*)(out + base) = v;
}

// cscatter: re-read edges, write packed records into per-(wg,bucket) slices
// rec = (dst&255)<<18 | c<<16 | src     (src < 65536, c < 4, dstlow < 256)
template<typename TI>
__device__ __forceinline__ void cscat_body(const TI* __restrict__ A,
                                           const unsigned int* __restrict__ cpos,
                                           unsigned int* __restrict__ recs,
                                           unsigned int* cur) {
    const int w = blockIdx.x, t = threadIdx.x;
    cur[t] = cpos[(size_t)t * NWG + w];
    __syncthreads();
    const int base = w * EPW;
    for (int i = t; i < EPW; i += 256) {
        const int e  = base + i;
        const int c  = e / NNZV;
        const int ei = e - c * NNZV;
        const int dst = (int)A[(size_t)(c * 2 + 0) * NNZV + ei];
        const int src = (int)A[(size_t)(c * 2 + 1) * NNZV + ei];
        if ((unsigned)dst >= NN || (unsigned)src >= NN) continue;
        const unsigned int pos = atomicAdd(&cur[dst >> 8], 1u);
        recs[pos] = ((unsigned)(dst & 255) << 18) | ((unsigned)c << 16) | (unsigned)src;
    }
}

__global__ __launch_bounds__(256) void cscatter_kernel(const void* __restrict__ A,
                                                       const unsigned int* __restrict__ cpos,
                                                       unsigned int* __restrict__ recs,
                                                       const int* __restrict__ flags) {
    __shared__ unsigned int cur[NBKT];
    if (flags[1]) cscat_body<long long>((const long long*)A, cpos, recs, cur);
    else          cscat_body<int>      ((const int*)A,       cpos, recs, cur);
}

// dfinal: one WG per bucket. LDS seg counts -> LDS scan -> offs/cnt + final
// edge_src written contiguously by a single WG.  seg_local = (dst&255)*4 + c
__global__ __launch_bounds__(256) void dfinal_kernel(const unsigned int* __restrict__ cpos,
                                                     const unsigned int* __restrict__ recs,
                                                     unsigned short* __restrict__ edge_src,
                                                     int* __restrict__ offs,
                                                     int* __restrict__ cnt) {
    __shared__ unsigned int scnt[1024], soff[1024];
    __shared__ unsigned int ts[256];
    const int b = blockIdx.x, t = threadIdx.x;
    const unsigned int base = cpos[(size_t)b * NWG];
    const unsigned int next = (b == NBKT - 1) ? (unsigned)TOTE : cpos[(size_t)(b + 1) * NWG];
    const int n = (int)(next - base);
    for (int j = t; j < 1024; j += 256) scnt[j] = 0;
    __syncthreads();
    for (int i = t; i < n; i += 256) {
        const unsigned int r = recs[base + i];
        const int seg = (int)(((r >> 18) & 255u) * 4u + ((r >> 16) & 3u));
        atomicAdd(&scnt[seg], 1u);
    }
    __syncthreads();
    // exclusive scan of scnt[1024]: thread t owns j = 4t..4t+3
    {
        const int j0 = t * 4;
        unsigned int v0 = scnt[j0], v1 = scnt[j0 + 1], v2 = scnt[j0 + 2], v3 = scnt[j0 + 3];
        unsigned int s = v0 + v1 + v2 + v3;
        ts[t] = s;
        __syncthreads();
        for (int off = 1; off < 256; off <<= 1) {
            unsigned int val = (t >= off) ? ts[t - off] : 0;
            __syncthreads();
            ts[t] += val;
            __syncthreads();
        }
        unsigned int ex = ts[t] - s;
        soff[j0] = ex; soff[j0 + 1] = ex + v0;
        soff[j0 + 2] = ex + v0 + v1; soff[j0 + 3] = ex + v0 + v1 + v2;
    }
    __syncthreads();
    // publish global offs/cnt:  global seg = dst*4 + c = b*1024 + j
    for (int j = t; j < 1024; j += 256) {
        const int dst = b * 256 + (j >> 2);
        if (dst < NN) {
            offs[b * 1024 + j] = (int)(base + soff[j]);
            cnt [b * 1024 + j] = (int)scnt[j];
        }
    }
    __syncthreads();
    // cursor pass (reuse soff as cursor), final contiguous edge_src write
    for (int i = t; i < n; i += 256) {
        const unsigned int r = recs[base + i];
        const int seg = (int)(((r >> 18) & 255u) * 4u + ((r >> 16) & 3u));
        const unsigned int pos = atomicAdd(&soff[seg], 1u);
        edge_src[base + pos] = (unsigned short)(r & 0xFFFFu);
    }
}

// ---------------------------------------------------------------------------
// Kernel 2: gather. Block per dst; wave c handles segment dst*4+c; lane = g.
// ---------------------------------------------------------------------------
__global__ __launch_bounds__(256) void gather_kernel(const unsigned short* __restrict__ edge_src,
                                                     const int* __restrict__ offs,
                                                     const int* __restrict__ cnt,
                                                     const unsigned short* __restrict__ XW,
                                                     float* __restrict__ H) {
    const int t   = threadIdx.x;
    const int c   = t >> 6;
    const int g   = t & 63;
    const int dst = blockIdx.x;
    const int seg = dst * 4 + c;
    const int beg = offs[seg];
    const int n   = cnt[seg];
    const unsigned short* xwg = XW + (size_t)c * NN * 64 + g;
    const unsigned short* ep  = edge_src + beg;
    float acc = 0.f;
    int e = 0;
    for (; e + 4 <= n; e += 4) {
        const int s0 = ep[e], s1 = ep[e + 1], s2 = ep[e + 2], s3 = ep[e + 3];
        const float a0 = bfu2f(xwg[(size_t)s0 * 64]);
        const float a1 = bfu2f(xwg[(size_t)s1 * 64]);
        const float a2 = bfu2f(xwg[(size_t)s2 * 64]);
        const float a3 = bfu2f(xwg[(size_t)s3 * 64]);
        acc += (a0 + a1) + (a2 + a3);
    }
    for (; e < n; ++e)
        acc += bfu2f(xwg[(size_t)ep[e] * 64]);
    H[(size_t)dst * 256 + c * 64 + g] = acc;
}

// ---------------------------------------------------------------------------
// Kernel 3: h = H @ W0 + b0  (K=256 -> 128 cols), fused BN partial sums.
// ---------------------------------------------------------------------------
template<typename TF>
__device__ __forceinline__ void l0_body(const float* __restrict__ H,
                                        const TF* __restrict__ W0,
                                        const TF* __restrict__ b0,
                                        float* __restrict__ h,
                                        float* __restrict__ stats,
                                        float* Hs, float* psum, float* psq) {
    const int n0 = blockIdx.x * 16;
    const int t  = threadIdx.x;
    {
        const float4* src4 = (const float4*)(H + (size_t)n0 * 256);
        float4* dst4 = (float4*)Hs;
        for (int i = t; i < 16 * 64; i += 256) dst4[i] = src4[i];
    }
    if (t < L0N) { psum[t] = 0.f; psq[t] = 0.f; }
    __syncthreads();
    const int j  = t & 127;
    const int rh = t >> 7;
    float acc[8];
    #pragma unroll
    for (int r = 0; r < 8; ++r) acc[r] = 0.f;
    for (int k = 0; k < 256; ++k) {
        float w = cvt(W0[k * 128 + j]);
        #pragma unroll
        for (int r = 0; r < 8; ++r)
            acc[r] = fmaf(Hs[(rh * 8 + r) * 256 + k], w, acc[r]);
    }
    const float bj = cvt(b0[j]);
    float s = 0.f, ss = 0.f;
    #pragma unroll
    for (int r = 0; r < 8; ++r) {
        float v = acc[r] + bj;
        h[(size_t)(n0 + rh * 8 + r) * 128 + j] = v;
        s += v; ss += v * v;
    }
    atomicAdd(&psum[j], s);
    atomicAdd(&psq[j], ss);
    __syncthreads();
    if (t < L0N) {
        atomicAdd(&stats[t],       psum[t]);
        atomicAdd(&stats[L0N + t], psq[t]);
    }
}

__global__ __launch_bounds__(256) void l0_kernel(const float* __restrict__ H,
                                                 const void* __restrict__ W0,
                                                 const void* __restrict__ b0,
                                                 float* __restrict__ h,
                                                 float* __restrict__ stats,
                                                 const int* __restrict__ flags) {
    __shared__ float Hs[16 * 256];
    __shared__ float psum[L0N], psq[L0N];
    if (flags[0]) l0_body<float>(H, (const float*)W0, (const float*)b0, h, stats, Hs, psum, psq);
    else          l0_body<bf16> (H, (const bf16*)W0,  (const bf16*)b0,  h, stats, Hs, psum, psq);
}

// ---------------------------------------------------------------------------
// Kernel 4: fold BN stats into per-column affine: bn(x) = a*x + b
// ---------------------------------------------------------------------------
template<typename TF>
__device__ __forceinline__ void bn_body(const float* __restrict__ stats,
                                        const TF* __restrict__ gamma,
                                        const TF* __restrict__ beta,
                                        float* __restrict__ coef) {
    const int j = threadIdx.x;
    const float invN = 1.0f / (float)NN;
    const float mean = stats[j] * invN;
    const float var  = stats[L0N + j] * invN - mean * mean;
    const float inv  = rsqrtf(var + 1e-5f);
    const float a = cvt(gamma[j]) * inv;
    const float b = cvt(beta[j]) - mean * a;
    coef[j] = a;
    coef[L0N + j] = b;
}

__global__ void bn_kernel(const float* __restrict__ stats,
                          const void* __restrict__ gamma,
                          const void* __restrict__ beta,
                          float* __restrict__ coef,
                          const int* __restrict__ flags) {
    if (flags[0]) bn_body<float>(stats, (const float*)gamma, (const float*)beta, coef);
    else          bn_body<bf16> (stats, (const bf16*)gamma,  (const bf16*)beta,  coef);
}

// ---------------------------------------------------------------------------
// Kernel 5: out = elu(bn(h)) @ W1 + b1  -> [N,64] in matching dtype
// ---------------------------------------------------------------------------
template<typename TF>
__device__ __forceinline__ void l1_body(const float* __restrict__ h,
                                        const float* __restrict__ coef,
                                        const TF* __restrict__ W1,
                                        const TF* __restrict__ b1,
                                        void* __restrict__ outv,
                                        float* Es) {
    const int n0 = blockIdx.x * 16;
    const int t  = threadIdx.x;
    for (int i = t; i < 16 * 128; i += 256) {
        const int k = i & 127;
        float v = h[(size_t)n0 * 128 + i];
        v = coef[k] * v + coef[L0N + k];
        Es[i] = v > 0.f ? v : expm1f(v);
    }
    __syncthreads();
    const int j  = t & 63;
    const int rq = t >> 6;
    float acc[4] = {0.f, 0.f, 0.f, 0.f};
    for (int k = 0; k < 128; ++k) {
        float w = cvt(W1[k * 64 + j]);
        #pragma unroll
        for (int r = 0; r < 4; ++r)
            acc[r] = fmaf(Es[(rq * 4 + r) * 128 + k], w, acc[r]);
    }
    const float bj = cvt(b1[j]);
    #pragma unroll
    for (int r = 0; r < 4; ++r) {
        const size_t oidx = (size_t)(n0 + rq * 4 + r) * 64 + j;
        const float v = acc[r] + bj;
        if (sizeof(TF) == 4) ((float*)outv)[oidx] = v;
        else                 ((unsigned short*)outv)[oidx] = tobits(v);
    }
}

__global__ __launch_bounds__(256) void l1_kernel(const float* __restrict__ h,
                                                 const float* __restrict__ coef,
                                                 const void* __restrict__ W1,
                                                 const void* __restrict__ b1,
                                                 void* __restrict__ out,
                                                 const int* __restrict__ flags) {
    __shared__ float Es[16 * 128];
    if (flags[0]) l1_body<float>(h, coef, (const float*)W1, (const float*)b1, out, Es);
    else          l1_body<bf16> (h, coef, (const bf16*)W1,  (const bf16*)b1,  out, Es);
}

// ---------------------------------------------------------------------------
// Workspace layout (bytes):
//   H        : [N,256] f32       @ 0            51,200,000
//     recs   : [3.2M] u32        @ 0            12,800,000  (ALIASES H; dead
//                                               before gather writes H)
//   stats    : [256]   f32       @ 51,200,000    1,024
//   coef     : [256]   f32       @ 51,201,024    1,024
//   flags    : [2]     i32       @ 51,202,048      256
//   XW       : [C,N,64] bf16     @ 51,202,304   25,600,000  (h aliases later)
//   hist     : [256*1024] u32    @ 76,802,304    1,048,576
//   cpos     : [256*1024] u32    @ 77,850,880    1,048,576
//   bsums    : [256] u32         @ 78,899,456    1,024
//   bscan    : [256] u32         @ 78,900,480    1,024
//   offs     : [200000] i32      @ 78,901,504      800,000
//   cnt      : [200000] i32      @ 79,701,504      800,000
//   edge_src : [3.2M] u16        @ 80,501,504    6,400,000
// total 86,901,504 B (~82.9 MiB)
// ---------------------------------------------------------------------------
extern "C" void kernel_launch(void* const* d_in, const int* in_sizes, int n_in,
                              void* d_out, int out_size, void* d_ws, size_t ws_size,
                              hipStream_t stream) {
    const void* A     = d_in[0];
    const void* X     = d_in[1];
    const void* Ws    = d_in[2];
    const void* W0    = d_in[3];
    const void* b0    = d_in[4];
    const void* gamma = d_in[5];
    const void* beta  = d_in[6];
    const void* W1    = d_in[7];
    const void* b1    = d_in[8];

    char* ws = (char*)d_ws;
    float*          H        = (float*)(ws);
    unsigned int*   recs     = (unsigned int*)(ws);            // alias H
    float*          stats    = (float*)(ws + 51200000);
    float*          coef     = (float*)(ws + 51201024);
    int*            flags    = (int*)  (ws + 51202048);
    unsigned short* XW       = (unsigned short*)(ws + 51202304);
    float*          h        = (float*)(ws + 51202304);        // alias XW
    unsigned int*   hist     = (unsigned int*)(ws + 76802304);
    unsigned int*   cpos     = (unsigned int*)(ws + 77850880);
    unsigned int*   bsums    = (unsigned int*)(ws + 78899456);
    unsigned int*   bscan    = (unsigned int*)(ws + 78900480);
    int*            offs     = (int*)  (ws + 78901504);
    int*            cnt      = (int*)  (ws + 79701504);
    unsigned short* edge_src = (unsigned short*)(ws + 80501504);

    detect_kernel<<<1, 256, 0, stream>>>((const unsigned int*)X, (const unsigned int*)A, flags);
    hipMemsetAsync(stats, 0, 1024, stream);   // zero BN stats every call

    xw_kernel     <<<NN / 16, 256, 0, stream>>>(X, Ws, XW, flags);
    hist_kernel   <<<NWG, 256, 0, stream>>>(A, hist, flags);
    scan1_kernel  <<<256, 256, 0, stream>>>(hist, cpos, bsums);
    scan2_kernel  <<<1, 256, 0, stream>>>(bsums, bscan);
    scan3_kernel  <<<256, 256, 0, stream>>>(cpos, bscan);
    cscatter_kernel<<<NWG, 256, 0, stream>>>(A, cpos, recs, flags);
    dfinal_kernel <<<NBKT - 60, 256, 0, stream>>>(cpos, recs, edge_src, offs, cnt); // 196 buckets
    gather_kernel <<<NN, 256, 0, stream>>>(edge_src, offs, cnt, XW, H);
    l0_kernel     <<<NN / 16, 256, 0, stream>>>(H, W0, b0, h, stats, flags);
    bn_kernel     <<<1, 128, 0, stream>>>(stats, gamma, beta, coef, flags);
    l1_kernel     <<<NN / 16, 256, 0, stream>>>(h, coef, W1, b1, d_out, flags);
}

// Round 5
// 378.487 us; speedup vs baseline: 4.2519x; 1.3385x over previous
//
#include <hip/hip_runtime.h>
#include <hip/hip_bf16.h>

#define NN    50000
#define CC    4
#define NNZV  800000
#define TOTE  (CC * NNZV)          // 3,200,000 edges
#define NWG   1024                 // workgroups for hist/cscatter
#define EPW   (TOTE / NWG)         // 3125 edges per WG (exact)
#define NBKT  256                  // dst buckets (dst >> 8); 196 non-empty
#define NRB   782                  // ceil(50000/64) row blocks for dense stages

using bf16 = __hip_bfloat16;
typedef short short8 __attribute__((ext_vector_type(8)));
typedef float f32x4  __attribute__((ext_vector_type(4)));

__device__ __forceinline__ float bfu2f(unsigned short u) {
    union { unsigned int i; float f; } v;
    v.i = ((unsigned int)u) << 16;
    return v.f;
}
__device__ __forceinline__ float cvt(float x) { return x; }
__device__ __forceinline__ float cvt(bf16 x)  { return __bfloat162float(x); }
__device__ __forceinline__ unsigned short tobits(float x) {
    bf16 t = __float2bfloat16(x);
    return *(unsigned short*)&t;
}

// ---------------------------------------------------------------------------
// Kernel 0: runtime dtype detection (proven rounds 2-4).
// flags[0] = 1 if float inputs are f32; flags[1] = 1 if A is int64
// ---------------------------------------------------------------------------
__global__ void detect_kernel(const unsigned int* __restrict__ Xw,
                              const unsigned int* __restrict__ Aw,
                              int* __restrict__ flags) {
    __shared__ int cnt[2];
    const int t = threadIdx.x;
    if (t < 2) cnt[t] = 0;
    __syncthreads();
    int c1 = 0;
    for (int i = t; i < 1024; i += 256) {
        unsigned b = (Xw[i] >> 7) & 0xFF;
        if (b >= 118 && b <= 134) c1++;
    }
    atomicAdd(&cnt[0], c1);
    int c2 = 0;
    if (t < 128) c2 = (Aw[2 * t + 1] == 0) ? 1 : 0;
    atomicAdd(&cnt[1], c2);
    __syncthreads();
    if (t == 0) {
        flags[0] = (cnt[0] < 512) ? 1 : 0;
        flags[1] = (cnt[1] >= 96) ? 1 : 0;
    }
}

// ---------------------------------------------------------------------------
// pack_kernel: pre-pack B-operands into MFMA fragment order (lane-contiguous
// 16B per fragment) + bias arrays to f32.
// B-frag layout for mfma_f32_16x16x32_bf16: lane=(q<<4)|n holds B[k0*32+q*8+j][n]
//   Wb  (l0): [k0<8][t8<8][lane<64][j<8]   <- W0[256][128]
//   Wb1 (l1): [k0<4][t4<4][lane<64][j<8]   <- W1[128][64]
//   Wbx (xw): [k0<2][tn<16][lane<64][j<8]  <- Ws[c][64][64], col=c*64+g
// ---------------------------------------------------------------------------
template<typename TF>
__device__ __forceinline__ void pack_body(const TF* __restrict__ W0, const TF* __restrict__ W1,
                                          const TF* __restrict__ Ws, const TF* __restrict__ b0,
                                          const TF* __restrict__ b1,
                                          unsigned short* __restrict__ Wb,
                                          unsigned short* __restrict__ Wb1,
                                          unsigned short* __restrict__ Wbx,
                                          float* __restrict__ bias0, float* __restrict__ bias1,
                                          int trip) {
    const int lane = trip & 63;
    const int q = lane >> 4, cI = lane & 15;
    if (trip < 4096) {
        const int k0 = trip >> 9, t8 = (trip >> 6) & 7;
        #pragma unroll
        for (int j = 0; j < 8; ++j)
            Wb[(size_t)trip * 8 + j] =
                tobits(cvt(W0[(size_t)(k0 * 32 + q * 8 + j) * 128 + t8 * 16 + cI]));
    } else if (trip < 5120) {
        const int u = trip - 4096;
        const int k0 = u >> 8, t4 = (u >> 6) & 3;
        #pragma unroll
        for (int j = 0; j < 8; ++j)
            Wb1[(size_t)u * 8 + j] =
                tobits(cvt(W1[(size_t)(k0 * 32 + q * 8 + j) * 64 + t4 * 16 + cI]));
    } else if (trip < 7168) {
        const int u = trip - 5120;
        const int k0 = u >> 10, tn = (u >> 6) & 15;
        const int col = tn * 16 + cI, c = col >> 6, g = col & 63;
        #pragma unroll
        for (int j = 0; j < 8; ++j)
            Wbx[(size_t)u * 8 + j] =
                tobits(cvt(Ws[((size_t)c * 64 + k0 * 32 + q * 8 + j) * 64 + g]));
    } else if (trip < 7296) {
        bias0[trip - 7168] = cvt(b0[trip - 7168]);
    } else if (trip < 7360) {
        bias1[trip - 7296] = cvt(b1[trip - 7296]);
    }
}

__global__ __launch_bounds__(256) void pack_kernel(const void* W0, const void* W1,
                                                   const void* Ws, const void* b0,
                                                   const void* b1,
                                                   unsigned short* Wb, unsigned short* Wb1,
                                                   unsigned short* Wbx,
                                                   float* bias0, float* bias1,
                                                   const int* __restrict__ flags) {
    const int trip = blockIdx.x * 256 + threadIdx.x;
    if (trip >= 7360) return;
    if (flags[0]) pack_body<float>((const float*)W0, (const float*)W1, (const float*)Ws,
                                   (const float*)b0, (const float*)b1, Wb, Wb1, Wbx, bias0, bias1, trip);
    else          pack_body<bf16> ((const bf16*)W0, (const bf16*)W1, (const bf16*)Ws,
                                   (const bf16*)b0, (const bf16*)b1, Wb, Wb1, Wbx, bias0, bias1, trip);
}

// ---------------------------------------------------------------------------
// xw_mfma: XW[c][n][g] = X @ Ws[c].  M=50000 K=64 N=256. 64-row tiles.
// ---------------------------------------------------------------------------
template<typename TF>
__device__ __forceinline__ void xw_stage(const TF* __restrict__ X, unsigned short* Xs,
                                         int n0, int t) {
    #pragma unroll
    for (int i = 0; i < 4; ++i) {
        const int r = (t >> 4) + i * 16;
        const int k = (t & 15) * 4;
        const int row = n0 + r;
        ushort4 o = make_ushort4(0, 0, 0, 0);
        if (row < NN) {
            o.x = tobits(cvt(X[(size_t)row * 64 + k + 0]));
            o.y = tobits(cvt(X[(size_t)row * 64 + k + 1]));
            o.z = tobits(cvt(X[(size_t)row * 64 + k + 2]));
            o.w = tobits(cvt(X[(size_t)row * 64 + k + 3]));
        }
        *(ushort4*)(&Xs[r * 80 + k]) = o;
    }
}

__global__ __launch_bounds__(256) void xw_mfma(const void* __restrict__ X,
                                               const unsigned short* __restrict__ Wbx,
                                               unsigned short* __restrict__ XW,
                                               const int* __restrict__ flags) {
    __shared__ unsigned short Xs[64 * 80];
    const int t = threadIdx.x, n0 = blockIdx.x * 64;
    if (flags[0]) xw_stage<float>((const float*)X, Xs, n0, t);
    else          xw_stage<bf16> ((const bf16*)X,  Xs, n0, t);
    __syncthreads();
    const int w = t >> 6, lane = t & 63;
    const int q = lane >> 4, cI = lane & 15;
    f32x4 acc[16];
    #pragma unroll
    for (int i = 0; i < 16; ++i) acc[i] = (f32x4){0.f, 0.f, 0.f, 0.f};
    const unsigned short* arow = &Xs[(w * 16 + cI) * 80 + q * 8];
    #pragma unroll
    for (int k0 = 0; k0 < 2; ++k0) {
        short8 a = *(const short8*)(arow + k0 * 32);
        #pragma unroll
        for (int tn = 0; tn < 16; ++tn) {
            short8 b = *(const short8*)(Wbx + ((size_t)(k0 * 16 + tn) * 64 + lane) * 8);
            acc[tn] = __builtin_amdgcn_mfma_f32_16x16x32_bf16(a, b, acc[tn], 0, 0, 0);
        }
    }
    const int rbase = n0 + w * 16 + q * 4;
    #pragma unroll
    for (int tn = 0; tn < 16; ++tn) {
        const int col = tn * 16 + cI, c = col >> 6, g = col & 63;
        #pragma unroll
        for (int r = 0; r < 4; ++r) {
            const int row = rbase + r;
            if (row < NN) XW[((size_t)c * NN + row) * 64 + g] = tobits(acc[tn][r]);
        }
    }
}

// ---------------------------------------------------------------------------
// CSR build, bucketed (unchanged from round 4): hist -> scan -> cscatter -> dfinal
// ---------------------------------------------------------------------------
template<typename TI>
__device__ __forceinline__ void hist_body(const TI* __restrict__ A,
                                          unsigned int* __restrict__ hist,
                                          unsigned int* lh) {
    const int w = blockIdx.x, t = threadIdx.x;
    lh[t] = 0;
    __syncthreads();
    const int base = w * EPW;
    for (int i = t; i < EPW; i += 256) {
        const int e  = base + i;
        const int c  = e / NNZV;
        const int ei = e - c * NNZV;
        const int dst = (int)A[(size_t)(c * 2) * NNZV + ei];
        if ((unsigned)dst < NN) atomicAdd(&lh[dst >> 8], 1u);
    }
    __syncthreads();
    hist[(size_t)t * NWG + w] = lh[t];
}

__global__ __launch_bounds__(256) void hist_kernel(const void* __restrict__ A,
                                                   unsigned int* __restrict__ hist,
                                                   const int* __restrict__ flags) {
    __shared__ unsigned int lh[NBKT];
    if (flags[1]) hist_body<long long>((const long long*)A, hist, lh);
    else          hist_body<int>      ((const int*)A,       hist, lh);
}

__global__ __launch_bounds__(256) void scan1_kernel(const unsigned int* __restrict__ in,
                                                    unsigned int* __restrict__ out,
                                                    unsigned int* __restrict__ bsums) {
    __shared__ unsigned int ts[256];
    const int t = threadIdx.x;
    const int base = blockIdx.x * 1024 + t * 4;
    uint4 v = *(const uint4*)(in + base);
    unsigned int s = v.x + v.y + v.z + v.w;
    ts[t] = s;
    __syncthreads();
    for (int off = 1; off < 256; off <<= 1) {
        unsigned int val = (t >= off) ? ts[t - off] : 0;
        __syncthreads();
        ts[t] += val;
        __syncthreads();
    }
    unsigned int ex = ts[t] - s;
    uint4 o;
    o.x = ex; o.y = ex + v.x; o.z = ex + v.x + v.y; o.w = ex + v.x + v.y + v.z;
    *(uint4*)(out + base) = o;
    if (t == 255) bsums[blockIdx.x] = ts[255];
}

__global__ __launch_bounds__(256) void scan2_kernel(const unsigned int* __restrict__ bsums,
                                                    unsigned int* __restrict__ bscan) {
    __shared__ unsigned int ts[256];
    const int t = threadIdx.x;
    unsigned int s = bsums[t];
    ts[t] = s;
    __syncthreads();
    for (int off = 1; off < 256; off <<= 1) {
        unsigned int val = (t >= off) ? ts[t - off] : 0;
        __syncthreads();
        ts[t] += val;
        __syncthreads();
    }
    bscan[t] = ts[t] - s;
}

__global__ __launch_bounds__(256) void scan3_kernel(unsigned int* __restrict__ out,
                                                    const unsigned int* __restrict__ bscan) {
    const int base = blockIdx.x * 1024 + threadIdx.x * 4;
    const unsigned int add = bscan[blockIdx.x];
    uint4 v = *(uint4*)(out + base);
    v.x += add; v.y += add; v.z += add; v.w += add;
    *(uint4*)(out + base) = v;
}

template<typename TI>
__device__ __forceinline__ void cscat_body(const TI* __restrict__ A,
                                           const unsigned int* __restrict__ cpos,
                                           unsigned int* __restrict__ recs,
                                           unsigned int* cur) {
    const int w = blockIdx.x, t = threadIdx.x;
    cur[t] = cpos[(size_t)t * NWG + w];
    __syncthreads();
    const int base = w * EPW;
    for (int i = t; i < EPW; i += 256) {
        const int e  = base + i;
        const int c  = e / NNZV;
        const int ei = e - c * NNZV;
        const int dst = (int)A[(size_t)(c * 2 + 0) * NNZV + ei];
        const int src = (int)A[(size_t)(c * 2 + 1) * NNZV + ei];
        if ((unsigned)dst >= NN || (unsigned)src >= NN) continue;
        const unsigned int pos = atomicAdd(&cur[dst >> 8], 1u);
        recs[pos] = ((unsigned)(dst & 255) << 18) | ((unsigned)c << 16) | (unsigned)src;
    }
}

__global__ __launch_bounds__(256) void cscatter_kernel(const void* __restrict__ A,
                                                       const unsigned int* __restrict__ cpos,
                                                       unsigned int* __restrict__ recs,
                                                       const int* __restrict__ flags) {
    __shared__ unsigned int cur[NBKT];
    if (flags[1]) cscat_body<long long>((const long long*)A, cpos, recs, cur);
    else          cscat_body<int>      ((const int*)A,       cpos, recs, cur);
}

__global__ __launch_bounds__(256) void dfinal_kernel(const unsigned int* __restrict__ cpos,
                                                     const unsigned int* __restrict__ recs,
                                                     unsigned short* __restrict__ edge_src,
                                                     int* __restrict__ offs,
                                                     int* __restrict__ cnt) {
    __shared__ unsigned int scnt[1024], soff[1024];
    __shared__ unsigned int ts[256];
    const int b = blockIdx.x, t = threadIdx.x;
    const unsigned int base = cpos[(size_t)b * NWG];
    const unsigned int next = cpos[(size_t)(b + 1) * NWG];
    const int n = (int)(next - base);
    for (int j = t; j < 1024; j += 256) scnt[j] = 0;
    __syncthreads();
    for (int i = t; i < n; i += 256) {
        const unsigned int r = recs[base + i];
        const int seg = (int)(((r >> 18) & 255u) * 4u + ((r >> 16) & 3u));
        atomicAdd(&scnt[seg], 1u);
    }
    __syncthreads();
    {
        const int j0 = t * 4;
        unsigned int v0 = scnt[j0], v1 = scnt[j0 + 1], v2 = scnt[j0 + 2], v3 = scnt[j0 + 3];
        unsigned int s = v0 + v1 + v2 + v3;
        ts[t] = s;
        __syncthreads();
        for (int off = 1; off < 256; off <<= 1) {
            unsigned int val = (t >= off) ? ts[t - off] : 0;
            __syncthreads();
            ts[t] += val;
            __syncthreads();
        }
        unsigned int ex = ts[t] - s;
        soff[j0] = ex; soff[j0 + 1] = ex + v0;
        soff[j0 + 2] = ex + v0 + v1; soff[j0 + 3] = ex + v0 + v1 + v2;
    }
    __syncthreads();
    for (int j = t; j < 1024; j += 256) {
        const int dst = b * 256 + (j >> 2);
        if (dst < NN) {
            offs[b * 1024 + j] = (int)(base + soff[j]);
            cnt [b * 1024 + j] = (int)scnt[j];
        }
    }
    __syncthreads();
    for (int i = t; i < n; i += 256) {
        const unsigned int r = recs[base + i];
        const int seg = (int)(((r >> 18) & 255u) * 4u + ((r >> 16) & 3u));
        const unsigned int pos = atomicAdd(&soff[seg], 1u);
        edge_src[base + pos] = (unsigned short)(r & 0xFFFFu);
    }
}

// ---------------------------------------------------------------------------
// gather: block per dst; wave c handles segment dst*4+c; lane = g.
// 8-way unroll for memory-level parallelism. H output is bf16 now.
// ---------------------------------------------------------------------------
__global__ __launch_bounds__(256) void gather_kernel(const unsigned short* __restrict__ edge_src,
                                                     const int* __restrict__ offs,
                                                     const int* __restrict__ cnt,
                                                     const unsigned short* __restrict__ XW,
                                                     unsigned short* __restrict__ H) {
    const int t   = threadIdx.x;
    const int c   = t >> 6;
    const int g   = t & 63;
    const int dst = blockIdx.x;
    const int seg = dst * 4 + c;
    const int beg = offs[seg];
    const int n   = cnt[seg];
    const unsigned short* xwg = XW + (size_t)c * NN * 64 + g;
    const unsigned short* ep  = edge_src + beg;
    float acc = 0.f;
    int e = 0;
    for (; e + 8 <= n; e += 8) {
        int s[8];
        #pragma unroll
        for (int j = 0; j < 8; ++j) s[j] = ep[e + j];
        float a[8];
        #pragma unroll
        for (int j = 0; j < 8; ++j) a[j] = bfu2f(xwg[(size_t)s[j] * 64]);
        acc += ((a[0] + a[1]) + (a[2] + a[3])) + ((a[4] + a[5]) + (a[6] + a[7]));
    }
    for (; e < n; ++e)
        acc += bfu2f(xwg[(size_t)ep[e] * 64]);
    H[(size_t)dst * 256 + c * 64 + g] = tobits(acc);
}

// ---------------------------------------------------------------------------
// l0_mfma: h = H @ W0 + b0 (M=50000 K=256 N=128) + fused BN partial sums.
// 64-row tile; wave w: rows w*16..w*16+15, all 128 cols (8 n-tiles).
// ---------------------------------------------------------------------------
__global__ __launch_bounds__(256) void l0_mfma(const unsigned short* __restrict__ Hg,
                                               const unsigned short* __restrict__ Wb,
                                               const float* __restrict__ bias0,
                                               unsigned short* __restrict__ hO,
                                               float* __restrict__ stats) {
    __shared__ unsigned short Hs[64 * 264];
    __shared__ float psum[128], psq[128];
    const int t = threadIdx.x;
    const int n0 = blockIdx.x * 64;
    #pragma unroll
    for (int i = 0; i < 16; ++i) {
        const int r = (t >> 6) + i * 4;
        const int k = (t & 63) * 4;
        const int row = n0 + r;
        ushort4 v = make_ushort4(0, 0, 0, 0);
        if (row < NN) v = *(const ushort4*)(Hg + (size_t)row * 256 + k);
        *(ushort4*)(&Hs[r * 264 + k]) = v;
    }
    if (t < 128) { psum[t] = 0.f; psq[t] = 0.f; }
    __syncthreads();
    const int w = t >> 6, lane = t & 63;
    const int q = lane >> 4, cI = lane & 15;
    f32x4 acc[8];
    #pragma unroll
    for (int i = 0; i < 8; ++i) acc[i] = (f32x4){0.f, 0.f, 0.f, 0.f};
    const unsigned short* arow = &Hs[(w * 16 + cI) * 264 + q * 8];
    #pragma unroll
    for (int k0 = 0; k0 < 8; ++k0) {
        short8 a = *(const short8*)(arow + k0 * 32);
        #pragma unroll
        for (int t8 = 0; t8 < 8; ++t8) {
            short8 b = *(const short8*)(Wb + ((size_t)(k0 * 8 + t8) * 64 + lane) * 8);
            acc[t8] = __builtin_amdgcn_mfma_f32_16x16x32_bf16(a, b, acc[t8], 0, 0, 0);
        }
    }
    const int rbase = n0 + w * 16 + q * 4;
    #pragma unroll
    for (int t8 = 0; t8 < 8; ++t8) {
        const int col = t8 * 16 + cI;
        const float bc = bias0[col];
        float s = 0.f, qq = 0.f;
        #pragma unroll
        for (int r = 0; r < 4; ++r) {
            const int row = rbase + r;
            float v = acc[t8][r] + bc;
            if (row < NN) hO[(size_t)row * 128 + col] = tobits(v);
            else          v = 0.f;
            s += v; qq += v * v;
        }
        s  += __shfl_xor(s, 16, 64);  s  += __shfl_xor(s, 32, 64);
        qq += __shfl_xor(qq, 16, 64); qq += __shfl_xor(qq, 32, 64);
        if (q == 0) { atomicAdd(&psum[col], s); atomicAdd(&psq[col], qq); }
    }
    __syncthreads();
    if (t < 128) { atomicAdd(&stats[t], psum[t]); atomicAdd(&stats[128 + t], psq[t]); }
}

// ---------------------------------------------------------------------------
// bn: fold stats into per-column affine
// ---------------------------------------------------------------------------
template<typename TF>
__device__ __forceinline__ void bn_body(const float* __restrict__ stats,
                                        const TF* __restrict__ gamma,
                                        const TF* __restrict__ beta,
                                        float* __restrict__ coef) {
    const int j = threadIdx.x;
    const float invN = 1.0f / (float)NN;
    const float mean = stats[j] * invN;
    const float var  = stats[128 + j] * invN - mean * mean;
    const float inv  = rsqrtf(var + 1e-5f);
    const float a = cvt(gamma[j]) * inv;
    const float b = cvt(beta[j]) - mean * a;
    coef[j] = a;
    coef[128 + j] = b;
}

__global__ void bn_kernel(const float* __restrict__ stats,
                          const void* __restrict__ gamma,
                          const void* __restrict__ beta,
                          float* __restrict__ coef,
                          const int* __restrict__ flags) {
    if (flags[0]) bn_body<float>(stats, (const float*)gamma, (const float*)beta, coef);
    else          bn_body<bf16> (stats, (const bf16*)gamma,  (const bf16*)beta,  coef);
}

// ---------------------------------------------------------------------------
// l1_mfma: out = elu(bn(h)) @ W1 + b1  (M=50000 K=128 N=64)
// BN affine + ELU applied during LDS staging.
// ---------------------------------------------------------------------------
__global__ __launch_bounds__(256) void l1_mfma(const unsigned short* __restrict__ hg,
                                               const float* __restrict__ coef,
                                               const unsigned short* __restrict__ Wb1,
                                               const float* __restrict__ bias1,
                                               void* __restrict__ outv,
                                               const int* __restrict__ flags) {
    __shared__ unsigned short Es[64 * 136];
    const int t = threadIdx.x;
    const int n0 = blockIdx.x * 64;
    #pragma unroll
    for (int i = 0; i < 8; ++i) {
        const int r = (t >> 5) + i * 8;
        const int k = (t & 31) * 4;
        const int row = n0 + r;
        ushort4 o = make_ushort4(0, 0, 0, 0);
        if (row < NN) {
            ushort4 v = *(const ushort4*)(hg + (size_t)row * 128 + k);
            float f0 = coef[k + 0] * bfu2f(v.x) + coef[128 + k + 0];
            float f1 = coef[k + 1] * bfu2f(v.y) + coef[128 + k + 1];
            float f2 = coef[k + 2] * bfu2f(v.z) + coef[128 + k + 2];
            float f3 = coef[k + 3] * bfu2f(v.w) + coef[128 + k + 3];
            f0 = f0 > 0.f ? f0 : expm1f(f0);
            f1 = f1 > 0.f ? f1 : expm1f(f1);
            f2 = f2 > 0.f ? f2 : expm1f(f2);
            f3 = f3 > 0.f ? f3 : expm1f(f3);
            o.x = tobits(f0); o.y = tobits(f1); o.z = tobits(f2); o.w = tobits(f3);
        }
        *(ushort4*)(&Es[r * 136 + k]) = o;
    }
    __syncthreads();
    const int w = t >> 6, lane = t & 63;
    const int q = lane >> 4, cI = lane & 15;
    f32x4 acc[4];
    #pragma unroll
    for (int i = 0; i < 4; ++i) acc[i] = (f32x4){0.f, 0.f, 0.f, 0.f};
    const unsigned short* arow = &Es[(w * 16 + cI) * 136 + q * 8];
    #pragma unroll
    for (int k0 = 0; k0 < 4; ++k0) {
        short8 a = *(const short8*)(arow + k0 * 32);
        #pragma unroll
        for (int t4 = 0; t4 < 4; ++t4) {
            short8 b = *(const short8*)(Wb1 + ((size_t)(k0 * 4 + t4) * 64 + lane) * 8);
            acc[t4] = __builtin_amdgcn_mfma_f32_16x16x32_bf16(a, b, acc[t4], 0, 0, 0);
        }
    }
    const int rbase = n0 + w * 16 + q * 4;
    const int f32out = flags[0];
    #pragma unroll
    for (int t4 = 0; t4 < 4; ++t4) {
        const int col = t4 * 16 + cI;
        const float bc = bias1[col];
        #pragma unroll
        for (int r = 0; r < 4; ++r) {
            const int row = rbase + r;
            if (row < NN) {
                const float v = acc[t4][r] + bc;
                if (f32out) ((float*)outv)[(size_t)row * 64 + col] = v;
                else        ((unsigned short*)outv)[(size_t)row * 64 + col] = tobits(v);
            }
        }
    }
}

// ---------------------------------------------------------------------------
// Workspace layout (bytes):
//   XW       : [C,N,64] bf16   @ 0            25,600,000
//   H        : [N,256]  bf16   @ 25,600,000   25,600,000
//   h        : [N,128]  bf16   @ 51,200,000   12,800,000
//   recs     : [3.2M]   u32    @ 64,000,000   12,800,000
//   hist     : [256*1024] u32  @ 76,800,000    1,048,576
//   cpos     : [256*1024] u32  @ 77,848,576    1,048,576
//   bsums    : [256] u32       @ 78,897,152        1,024
//   bscan    : [256] u32       @ 78,898,176        1,024
//   offs     : [200000] i32    @ 78,899,200      800,000
//   cnt      : [200000] i32    @ 79,699,200      800,000
//   edge_src : [3.2M] u16      @ 80,499,200    6,400,000
//   stats    : [256] f32       @ 86,899,200        1,024
//   coef     : [256] f32       @ 86,900,224        1,024
//   flags    : [2] i32         @ 86,901,248          256
//   Wb       : u16             @ 86,901,504       65,536
//   Wb1      : u16             @ 86,967,040       16,384
//   Wbx      : u16             @ 86,983,424       32,768
//   bias0    : f32[128]        @ 87,016,192          512
//   bias1    : f32[64]         @ 87,016,704          256
// total 87,016,960 B (~83.0 MiB)
// ---------------------------------------------------------------------------
extern "C" void kernel_launch(void* const* d_in, const int* in_sizes, int n_in,
                              void* d_out, int out_size, void* d_ws, size_t ws_size,
                              hipStream_t stream) {
    const void* A     = d_in[0];
    const void* X     = d_in[1];
    const void* Ws    = d_in[2];
    const void* W0    = d_in[3];
    const void* b0    = d_in[4];
    const void* gamma = d_in[5];
    const void* beta  = d_in[6];
    const void* W1    = d_in[7];
    const void* b1    = d_in[8];

    char* ws = (char*)d_ws;
    unsigned short* XW       = (unsigned short*)(ws);
    unsigned short* H        = (unsigned short*)(ws + 25600000);
    unsigned short* h        = (unsigned short*)(ws + 51200000);
    unsigned int*   recs     = (unsigned int*)  (ws + 64000000);
    unsigned int*   hist     = (unsigned int*)  (ws + 76800000);
    unsigned int*   cpos     = (unsigned int*)  (ws + 77848576);
    unsigned int*   bsums    = (unsigned int*)  (ws + 78897152);
    unsigned int*   bscan    = (unsigned int*)  (ws + 78898176);
    int*            offs     = (int*)           (ws + 78899200);
    int*            cnt      = (int*)           (ws + 79699200);
    unsigned short* edge_src = (unsigned short*)(ws + 80499200);
    float*          stats    = (float*)         (ws + 86899200);
    float*          coef     = (float*)         (ws + 86900224);
    int*            flags    = (int*)           (ws + 86901248);
    unsigned short* Wb       = (unsigned short*)(ws + 86901504);
    unsigned short* Wb1      = (unsigned short*)(ws + 86967040);
    unsigned short* Wbx      = (unsigned short*)(ws + 86983424);
    float*          bias0    = (float*)         (ws + 87016192);
    float*          bias1    = (float*)         (ws + 87016704);

    detect_kernel<<<1, 256, 0, stream>>>((const unsigned int*)X, (const unsigned int*)A, flags);
    hipMemsetAsync(stats, 0, 1024, stream);

    pack_kernel   <<<29, 256, 0, stream>>>(W0, W1, Ws, b0, b1, Wb, Wb1, Wbx, bias0, bias1, flags);
    xw_mfma       <<<NRB, 256, 0, stream>>>(X, Wbx, XW, flags);
    hist_kernel   <<<NWG, 256, 0, stream>>>(A, hist, flags);
    scan1_kernel  <<<256, 256, 0, stream>>>(hist, cpos, bsums);
    scan2_kernel  <<<1, 256, 0, stream>>>(bsums, bscan);
    scan3_kernel  <<<256, 256, 0, stream>>>(cpos, bscan);
    cscatter_kernel<<<NWG, 256, 0, stream>>>(A, cpos, recs, flags);
    dfinal_kernel <<<196, 256, 0, stream>>>(cpos, recs, edge_src, offs, cnt);
    gather_kernel <<<NN, 256, 0, stream>>>(edge_src, offs, cnt, XW, H);
    l0_mfma       <<<NRB, 256, 0, stream>>>(H, Wb, bias0, h, stats);
    bn_kernel     <<<1, 128, 0, stream>>>(stats, gamma, beta, coef, flags);
    l1_mfma       <<<NRB, 256, 0, stream>>>(h, coef, Wb1, bias1, d_out, flags);
}